// Round 2
// baseline (228.965 us; speedup 1.0000x reference)
//
#include <hip/hip_runtime.h>
#include <hip/hip_cooperative_groups.h>

namespace cg = cooperative_groups;

#define NN 50000
#define NE 800000
#define NB 782        // ceil(NN/64)
#define TOTF 114688   // frag elems: W1 (8kc*4096=32768) + 5 matrices * 16384
#define GTHREADS (NB * 512)

typedef unsigned short u16;
typedef unsigned int u32;
typedef __attribute__((ext_vector_type(8))) short s8v;   // 8 bf16 = 4 VGPRs (MFMA A/B frag)
typedef __attribute__((ext_vector_type(4))) float f4v;   // MFMA C/D frag

// split fp32 into hi (truncated bf16) + lo (bf16 of remainder): f ~= hi + lo
__device__ __forceinline__ void split2(float f, u16& h, u16& lo) {
    u32 u = __float_as_uint(f);
    h = (u16)(u >> 16);
    float r = f - __uint_as_float(u & 0xFFFF0000u);   // exact
    lo = (u16)(__float_as_uint(r) >> 16);
}

// ======================= fallback-path kernels (verbatim round-0) =======================

__global__ void mask_scatter_k(const int* __restrict__ dst, float* __restrict__ mask) {
    int i = blockIdx.x * blockDim.x + threadIdx.x;
    if (i < NE) mask[dst[i]] = 1.0f;
}

__global__ void prep_w_k(const float* __restrict__ W1, const float* __restrict__ W2,
                         const float* __restrict__ Wv, const float* __restrict__ Wo,
                         u16* __restrict__ fh, u16* __restrict__ fl) {
    int idx = blockIdx.x * 256 + threadIdx.x;
    if (idx >= TOTF) return;
    const float* W;
    int local;
    if (idx < 32768) { W = W1; local = idx; }
    else {
        int t = idx - 32768;
        int m = t >> 14;
        local = t & 16383;
        if (m == 0) W = W2;
        else if (m == 1) W = Wv;
        else if (m == 2) W = Wo;
        else if (m == 3) W = Wv + 16384;
        else W = Wo + 16384;
    }
    int j = local & 7, l = (local >> 3) & 63, nt = (local >> 9) & 7, kc = local >> 12;
    int k = kc * 32 + ((l >> 4) << 3) + j;
    int n = nt * 16 + (l & 15);
    u16 h, lo;
    split2(W[k * 128 + n], h, lo);
    fh[idx] = h;
    fl[idx] = lo;
}

__global__ __launch_bounds__(64)
void redstats_k(const float* __restrict__ pst, float* __restrict__ st) {
    int c = blockIdx.x;
    float s = 0.f;
    for (int b = threadIdx.x; b < NB; b += 64) s += pst[(size_t)b * 256 + c];
    s += __shfl_xor(s, 1);  s += __shfl_xor(s, 2);  s += __shfl_xor(s, 4);
    s += __shfl_xor(s, 8);  s += __shfl_xor(s, 16); s += __shfl_xor(s, 32);
    if (threadIdx.x == 0) st[c] = s;
}

template<int KC, int FOLD, int STATS>
__global__ __launch_bounds__(512, 6)
void mgemm_k(const float* __restrict__ A,
             const u16* __restrict__ fh, const u16* __restrict__ fl,
             const float* __restrict__ bias,
             const float* __restrict__ fst,
             const float* __restrict__ fg, const float* __restrict__ fbe,
             float* __restrict__ pst,
             float* __restrict__ C) {
    constexpr int KP = KC / 4;
    __shared__ __align__(16) u16 Ah[64][136];
    __shared__ __align__(16) u16 Al[64][136];
    __shared__ float scl[128], shf[128];
    const int tid = threadIdx.x;
    const int l = tid & 63, w = tid >> 6;
    const int q = l >> 4, cc = l & 15;
    const int sl = w >> 1, hf = w & 1;
    const int row0 = blockIdx.x * 64;

    if (FOLD && tid < 128) {
        float mean = fst[tid] * (1.0f / NN);
        float var = fst[128 + tid] * (1.0f / NN) - mean * mean;
        float rstd = rsqrtf(var + 1e-5f);
        float ga = fg[tid] * rstd;
        scl[tid] = ga;
        shf[tid] = fbe[tid] - mean * ga;
    }

    f4v zf = {0.f, 0.f, 0.f, 0.f};
    f4v acc[4];
#pragma unroll
    for (int t = 0; t < 4; ++t) acc[t] = zf;

    for (int p = 0; p < KP; ++p) {
        if (p > 0 || FOLD) __syncthreads();
#pragma unroll
        for (int it = 0; it < 4; ++it) {
            int lin = tid + 512 * it;
            int r = lin >> 5;
            int c4 = (lin & 31) * 4;
            int gr = row0 + r; if (gr > NN - 1) gr = NN - 1;
            float4 f = *(const float4*)(A + (size_t)gr * (KC * 32) + p * 128 + c4);
            float v[4] = {f.x, f.y, f.z, f.w};
            if (FOLD) {
#pragma unroll
                for (int m = 0; m < 4; ++m) {
                    float t = v[m] * scl[c4 + m] + shf[c4 + m];
                    v[m] = t > 0.f ? t : 0.f;
                }
            }
            ushort4 uh, ul;
            split2(v[0], uh.x, ul.x); split2(v[1], uh.y, ul.y);
            split2(v[2], uh.z, ul.z); split2(v[3], uh.w, ul.w);
            *(ushort4*)&Ah[r][c4] = uh;
            *(ushort4*)&Al[r][c4] = ul;
        }
        __syncthreads();
#pragma unroll
        for (int kc = 0; kc < 4; ++kc) {
            int kcg = p * 4 + kc;
            s8v ah = *(const s8v*)&Ah[16 * sl + cc][kc * 32 + q * 8];
            s8v al = *(const s8v*)&Al[16 * sl + cc][kc * 32 + q * 8];
#pragma unroll
            for (int t = 0; t < 4; ++t) {
                const int fo = kcg * 4096 + (4 * hf + t) * 512 + l * 8;
                s8v bh = *(const s8v*)(fh + fo);
                s8v bl = *(const s8v*)(fl + fo);
                acc[t] = __builtin_amdgcn_mfma_f32_16x16x32_bf16(ah, bh, acc[t], 0, 0, 0);
                acc[t] = __builtin_amdgcn_mfma_f32_16x16x32_bf16(ah, bl, acc[t], 0, 0, 0);
                acc[t] = __builtin_amdgcn_mfma_f32_16x16x32_bf16(al, bh, acc[t], 0, 0, 0);
            }
        }
    }

    float ps[4], pq[4];
#pragma unroll
    for (int t = 0; t < 4; ++t) { ps[t] = 0.f; pq[t] = 0.f; }
#pragma unroll
    for (int t = 0; t < 4; ++t) {
        int col = (4 * hf + t) * 16 + cc;
        float bb = bias[col];
#pragma unroll
        for (int r = 0; r < 4; ++r) {
            int gr = row0 + 16 * sl + q * 4 + r;
            float val = acc[t][r] + bb;
            if (gr < NN) {
                C[(size_t)gr * 128 + col] = val;
                if (STATS) { ps[t] += val; pq[t] += val * val; }
            }
        }
    }
    if (STATS) {
        __syncthreads();
        float* wredS = (float*)&Ah[0][0];
        float* wredQ = wredS + 512;
#pragma unroll
        for (int t = 0; t < 4; ++t) {
            ps[t] += __shfl_xor(ps[t], 16); ps[t] += __shfl_xor(ps[t], 32);
            pq[t] += __shfl_xor(pq[t], 16); pq[t] += __shfl_xor(pq[t], 32);
        }
        if (l < 16) {
#pragma unroll
            for (int t = 0; t < 4; ++t) {
                int col = (4 * hf + t) * 16 + l;
                wredS[sl * 128 + col] = ps[t];
                wredQ[sl * 128 + col] = pq[t];
            }
        }
        __syncthreads();
        if (tid < 256) {
            int c = tid & 127;
            const float* src = (tid < 128) ? wredS : wredQ;
            pst[(size_t)blockIdx.x * 256 + tid] =
                src[c] + src[128 + c] + src[256 + c] + src[384 + c];
        }
    }
}

__global__ __launch_bounds__(512, 6)
void mmega_k(const float* __restrict__ X,
             const u16* __restrict__ fh, const u16* __restrict__ fl,
             const float* __restrict__ bv, const float* __restrict__ bo,
             const float* __restrict__ fst,
             const float* __restrict__ fg, const float* __restrict__ fbe,
             const float* __restrict__ mask, float* __restrict__ out) {
    __shared__ __align__(16) u16 Ah[64][136];
    __shared__ __align__(16) u16 Al[64][136];
    __shared__ float scl[128], shf[128];
    const int tid = threadIdx.x;
    const int l = tid & 63, w = tid >> 6;
    const int q = l >> 4, cc = l & 15;
    const int sl = w >> 1, hf = w & 1;
    const int row0 = blockIdx.x * 64;

    if (tid < 128) {
        float mean = fst[tid] * (1.0f / NN);
        float var = fst[128 + tid] * (1.0f / NN) - mean * mean;
        float rstd = rsqrtf(var + 1e-5f);
        float ga = fg[tid] * rstd;
        scl[tid] = ga;
        shf[tid] = fbe[tid] - mean * ga;
    }
    __syncthreads();

    float rm[4];
#pragma unroll
    for (int r = 0; r < 4; ++r) {
        int gr = row0 + 16 * sl + q * 4 + r;
        rm[r] = (gr < NN) ? mask[gr] : 0.f;
    }

#pragma unroll
    for (int it = 0; it < 4; ++it) {
        int lin = tid + 512 * it;
        int r = lin >> 5;
        int c4 = (lin & 31) * 4;
        int gr = row0 + r; if (gr > NN - 1) gr = NN - 1;
        float4 f = *(const float4*)(X + (size_t)gr * 128 + c4);
        float v[4] = {f.x, f.y, f.z, f.w};
        ushort4 uh, ul;
#pragma unroll
        for (int m = 0; m < 4; ++m) {
            float t = v[m] * scl[c4 + m] + shf[c4 + m];
            v[m] = t > 0.f ? t : 0.f;
        }
        split2(v[0], uh.x, ul.x); split2(v[1], uh.y, ul.y);
        split2(v[2], uh.z, ul.z); split2(v[3], uh.w, ul.w);
        *(ushort4*)&Ah[r][c4] = uh;
        *(ushort4*)&Al[r][c4] = ul;
    }
    __syncthreads();

    f4v zf = {0.f, 0.f, 0.f, 0.f};
    for (int s = 0; s < 4; ++s) {
        const u16* WH = fh + s * 16384;
        const u16* WL = fl + s * 16384;
        const float* bp = (s == 0) ? bv : (s == 1) ? bo : (s == 2) ? (bv + 128) : (bo + 128);

        f4v acc[4];
#pragma unroll
        for (int t = 0; t < 4; ++t) acc[t] = zf;
#pragma unroll
        for (int kc = 0; kc < 4; ++kc) {
            s8v ah = *(const s8v*)&Ah[16 * sl + cc][kc * 32 + q * 8];
            s8v al = *(const s8v*)&Al[16 * sl + cc][kc * 32 + q * 8];
#pragma unroll
            for (int t = 0; t < 4; ++t) {
                const int fo = kc * 4096 + (4 * hf + t) * 512 + l * 8;
                s8v bh = *(const s8v*)(WH + fo);
                s8v bl = *(const s8v*)(WL + fo);
                acc[t] = __builtin_amdgcn_mfma_f32_16x16x32_bf16(ah, bh, acc[t], 0, 0, 0);
                acc[t] = __builtin_amdgcn_mfma_f32_16x16x32_bf16(ah, bl, acc[t], 0, 0, 0);
                acc[t] = __builtin_amdgcn_mfma_f32_16x16x32_bf16(al, bh, acc[t], 0, 0, 0);
            }
        }

        if (s == 3) {
#pragma unroll
            for (int t = 0; t < 4; ++t) {
                int col = (4 * hf + t) * 16 + cc;
                float bb = bp[col];
#pragma unroll
                for (int r = 0; r < 4; ++r) {
                    int gr = row0 + 16 * sl + q * 4 + r;
                    if (gr < NN)
                        out[(size_t)gr * 128 + col] = fmaxf(acc[t][r] + bb, 0.f);
                }
            }
        } else {
            __syncthreads();
#pragma unroll
            for (int t = 0; t < 4; ++t) {
                int col = (4 * hf + t) * 16 + cc;
                float bb = bp[col];
#pragma unroll
                for (int r = 0; r < 4; ++r) {
                    int rl = 16 * sl + q * 4 + r;
                    float val = acc[t][r] + bb;
                    val = (s == 1) ? fmaxf(val, 0.f) : val * rm[r];
                    u16 h, lo; split2(val, h, lo);
                    Ah[rl][col] = h;
                    Al[rl][col] = lo;
                }
            }
            __syncthreads();
        }
    }
}

// ======================= fused cooperative kernel =======================
// prep -> enc1 -> red1 -> enc2 -> red2 -> attn chain; intermediates live in registers.
// __launch_bounds__(512,8) forces VGPR<=64 so 4 blocks/CU co-reside (782 blocks).
__global__ __launch_bounds__(512, 8)
void fused_k(const float* __restrict__ x, const int* __restrict__ ei,
             const float* __restrict__ W1, const float* __restrict__ b1,
             const float* __restrict__ g1, const float* __restrict__ be1,
             const float* __restrict__ W2, const float* __restrict__ b2,
             const float* __restrict__ g2, const float* __restrict__ be2,
             const float* __restrict__ Wv, const float* __restrict__ bv,
             const float* __restrict__ Wo, const float* __restrict__ bo,
             float* __restrict__ mask, float* __restrict__ st,
             float* __restrict__ pst,
             u16* __restrict__ fh, u16* __restrict__ fl,
             float* __restrict__ out) {
    __shared__ __align__(16) u16 Ah[64][136];
    __shared__ __align__(16) u16 Al[64][136];
    const int tid = threadIdx.x;
    const int bid = blockIdx.x;
    const int l = tid & 63, w = tid >> 6;
    const int q = l >> 4, cc = l & 15;
    const int sl = w >> 1, hf = w & 1;
    const int row0 = bid * 64;
    const int gidx = bid * 512 + tid;

    cg::grid_group grid = cg::this_grid();

    // ---- phase 0: weight frag prep + mask zero ----
    if (gidx < TOTF) {
        const float* W;
        int local;
        if (gidx < 32768) { W = W1; local = gidx; }
        else {
            int tt = gidx - 32768;
            int m = tt >> 14;
            local = tt & 16383;
            if (m == 0) W = W2;
            else if (m == 1) W = Wv;
            else if (m == 2) W = Wo;
            else if (m == 3) W = Wv + 16384;
            else W = Wo + 16384;
        }
        int j = local & 7, el = (local >> 3) & 63, nt = (local >> 9) & 7, kc = local >> 12;
        int k = kc * 32 + ((el >> 4) << 3) + j;
        int n = nt * 16 + (el & 15);
        u16 h, lo;
        split2(W[k * 128 + n], h, lo);
        fh[gidx] = h;
        fl[gidx] = lo;
    }
    if (gidx < NN) mask[gidx] = 0.f;

    grid.sync();

    // ---- phase E1: enc1 GEMM x@W1 (K=256, 2 passes) ----
    f4v zf = {0.f, 0.f, 0.f, 0.f};
    f4v acc[4];
#pragma unroll
    for (int t = 0; t < 4; ++t) acc[t] = zf;

    for (int p = 0; p < 2; ++p) {
        if (p) __syncthreads();
#pragma unroll
        for (int it = 0; it < 4; ++it) {
            int lin = tid + 512 * it;
            int r = lin >> 5;
            int c4 = (lin & 31) * 4;
            int gr = row0 + r; if (gr > NN - 1) gr = NN - 1;
            float4 f = *(const float4*)(x + (size_t)gr * 256 + p * 128 + c4);
            ushort4 uh, ul;
            split2(f.x, uh.x, ul.x); split2(f.y, uh.y, ul.y);
            split2(f.z, uh.z, ul.z); split2(f.w, uh.w, ul.w);
            *(ushort4*)&Ah[r][c4] = uh;
            *(ushort4*)&Al[r][c4] = ul;
        }
        __syncthreads();
#pragma unroll
        for (int kc = 0; kc < 4; ++kc) {
            int kcg = p * 4 + kc;
            s8v ah = *(const s8v*)&Ah[16 * sl + cc][kc * 32 + q * 8];
            s8v al = *(const s8v*)&Al[16 * sl + cc][kc * 32 + q * 8];
#pragma unroll
            for (int t = 0; t < 4; ++t) {
                const int fo = kcg * 4096 + (4 * hf + t) * 512 + l * 8;
                s8v bh = *(const s8v*)(fh + fo);
                s8v bl = *(const s8v*)(fl + fo);
                acc[t] = __builtin_amdgcn_mfma_f32_16x16x32_bf16(ah, bh, acc[t], 0, 0, 0);
                acc[t] = __builtin_amdgcn_mfma_f32_16x16x32_bf16(ah, bl, acc[t], 0, 0, 0);
                acc[t] = __builtin_amdgcn_mfma_f32_16x16x32_bf16(al, bh, acc[t], 0, 0, 0);
            }
        }
    }
    {
        float ps[4], pq[4];
#pragma unroll
        for (int t = 0; t < 4; ++t) {
            int col = (4 * hf + t) * 16 + cc;
            float bb = b1[col];
            ps[t] = 0.f; pq[t] = 0.f;
#pragma unroll
            for (int r = 0; r < 4; ++r) {
                float val = acc[t][r] + bb;
                acc[t][r] = val;
                int gr = row0 + 16 * sl + q * 4 + r;
                if (gr < NN) { ps[t] += val; pq[t] += val * val; }
            }
        }
        __syncthreads();
        float* wredS = (float*)&Ah[0][0];
        float* wredQ = wredS + 512;
#pragma unroll
        for (int t = 0; t < 4; ++t) {
            ps[t] += __shfl_xor(ps[t], 16); ps[t] += __shfl_xor(ps[t], 32);
            pq[t] += __shfl_xor(pq[t], 16); pq[t] += __shfl_xor(pq[t], 32);
        }
        if (l < 16) {
#pragma unroll
            for (int t = 0; t < 4; ++t) {
                int col = (4 * hf + t) * 16 + l;
                wredS[sl * 128 + col] = ps[t];
                wredQ[sl * 128 + col] = pq[t];
            }
        }
        __syncthreads();
        if (tid < 256) {
            int c = tid & 127;
            const float* srcp = (tid < 128) ? wredS : wredQ;
            pst[(size_t)bid * 256 + tid] =
                srcp[c] + srcp[128 + c] + srcp[256 + c] + srcp[384 + c];
        }
    }

    grid.sync();

    // ---- red1 (exact redstats_k replica) + edge scatter ----
    if (bid < 256 && tid < 64) {
        float s = 0.f;
        for (int b = tid; b < NB; b += 64) s += pst[(size_t)b * 256 + bid];
        s += __shfl_xor(s, 1);  s += __shfl_xor(s, 2);  s += __shfl_xor(s, 4);
        s += __shfl_xor(s, 8);  s += __shfl_xor(s, 16); s += __shfl_xor(s, 32);
        if (tid == 0) st[bid] = s;
    }
    {
        const int* dstv = ei + NE;
        for (int eg = gidx; eg < NE; eg += GTHREADS) mask[dstv[eg]] = 1.0f;
    }

    grid.sync();

    // ---- phase E2: fold bn1+relu (from registers), enc2 GEMM ----
#pragma unroll
    for (int t = 0; t < 4; ++t) {
        int col = (4 * hf + t) * 16 + cc;
        float mean = st[col] * (1.0f / NN);
        float var = st[128 + col] * (1.0f / NN) - mean * mean;
        float ga = g1[col] * rsqrtf(var + 1e-5f);
        float sh = be1[col] - mean * ga;
#pragma unroll
        for (int r = 0; r < 4; ++r) {
            float v = acc[t][r] * ga + sh;
            v = v > 0.f ? v : 0.f;
            u16 h, lo; split2(v, h, lo);
            int rl = 16 * sl + q * 4 + r;
            Ah[rl][col] = h;
            Al[rl][col] = lo;
        }
    }
    __syncthreads();

    f4v acc2[4];
#pragma unroll
    for (int t = 0; t < 4; ++t) acc2[t] = zf;
#pragma unroll
    for (int kc = 0; kc < 4; ++kc) {
        s8v ah = *(const s8v*)&Ah[16 * sl + cc][kc * 32 + q * 8];
        s8v al = *(const s8v*)&Al[16 * sl + cc][kc * 32 + q * 8];
#pragma unroll
        for (int t = 0; t < 4; ++t) {
            const int fo = 32768 + kc * 4096 + (4 * hf + t) * 512 + l * 8;
            s8v bh = *(const s8v*)(fh + fo);
            s8v bl = *(const s8v*)(fl + fo);
            acc2[t] = __builtin_amdgcn_mfma_f32_16x16x32_bf16(ah, bh, acc2[t], 0, 0, 0);
            acc2[t] = __builtin_amdgcn_mfma_f32_16x16x32_bf16(ah, bl, acc2[t], 0, 0, 0);
            acc2[t] = __builtin_amdgcn_mfma_f32_16x16x32_bf16(al, bh, acc2[t], 0, 0, 0);
        }
    }
    {
        float ps[4], pq[4];
#pragma unroll
        for (int t = 0; t < 4; ++t) {
            int col = (4 * hf + t) * 16 + cc;
            float bb = b2[col];
            ps[t] = 0.f; pq[t] = 0.f;
#pragma unroll
            for (int r = 0; r < 4; ++r) {
                float val = acc2[t][r] + bb;
                acc2[t][r] = val;
                int gr = row0 + 16 * sl + q * 4 + r;
                if (gr < NN) { ps[t] += val; pq[t] += val * val; }
            }
        }
        __syncthreads();
        float* wredS = (float*)&Ah[0][0];
        float* wredQ = wredS + 512;
#pragma unroll
        for (int t = 0; t < 4; ++t) {
            ps[t] += __shfl_xor(ps[t], 16); ps[t] += __shfl_xor(ps[t], 32);
            pq[t] += __shfl_xor(pq[t], 16); pq[t] += __shfl_xor(pq[t], 32);
        }
        if (l < 16) {
#pragma unroll
            for (int t = 0; t < 4; ++t) {
                int col = (4 * hf + t) * 16 + l;
                wredS[sl * 128 + col] = ps[t];
                wredQ[sl * 128 + col] = pq[t];
            }
        }
        __syncthreads();
        if (tid < 256) {
            int c = tid & 127;
            const float* srcp = (tid < 128) ? wredS : wredQ;
            pst[(size_t)bid * 256 + tid] =
                srcp[c] + srcp[128 + c] + srcp[256 + c] + srcp[384 + c];
        }
    }

    grid.sync();

    // ---- red2 ----
    if (bid < 256 && tid < 64) {
        float s = 0.f;
        for (int b = tid; b < NB; b += 64) s += pst[(size_t)b * 256 + bid];
        s += __shfl_xor(s, 1);  s += __shfl_xor(s, 2);  s += __shfl_xor(s, 4);
        s += __shfl_xor(s, 8);  s += __shfl_xor(s, 16); s += __shfl_xor(s, 32);
        if (tid == 0) st[256 + bid] = s;
    }

    grid.sync();

    // ---- phase M: fold bn2+relu, 4-stage attn chain ----
    float rm[4];
#pragma unroll
    for (int r = 0; r < 4; ++r) {
        int gr = row0 + 16 * sl + q * 4 + r;
        rm[r] = (gr < NN) ? mask[gr] : 0.f;
    }
#pragma unroll
    for (int t = 0; t < 4; ++t) {
        int col = (4 * hf + t) * 16 + cc;
        float mean = st[256 + col] * (1.0f / NN);
        float var = st[384 + col] * (1.0f / NN) - mean * mean;
        float ga = g2[col] * rsqrtf(var + 1e-5f);
        float sh = be2[col] - mean * ga;
#pragma unroll
        for (int r = 0; r < 4; ++r) {
            float v = acc2[t][r] * ga + sh;
            v = v > 0.f ? v : 0.f;
            u16 h, lo; split2(v, h, lo);
            int rl = 16 * sl + q * 4 + r;
            Ah[rl][col] = h;
            Al[rl][col] = lo;
        }
    }
    __syncthreads();

    for (int s3 = 0; s3 < 4; ++s3) {
        const u16* WH = fh + 49152 + s3 * 16384;
        const u16* WL = fl + 49152 + s3 * 16384;
        const float* bp = (s3 == 0) ? bv : (s3 == 1) ? bo : (s3 == 2) ? (bv + 128) : (bo + 128);

        f4v a3[4];
#pragma unroll
        for (int t = 0; t < 4; ++t) a3[t] = zf;
#pragma unroll
        for (int kc = 0; kc < 4; ++kc) {
            s8v ah = *(const s8v*)&Ah[16 * sl + cc][kc * 32 + q * 8];
            s8v al = *(const s8v*)&Al[16 * sl + cc][kc * 32 + q * 8];
#pragma unroll
            for (int t = 0; t < 4; ++t) {
                const int fo = kc * 4096 + (4 * hf + t) * 512 + l * 8;
                s8v bh = *(const s8v*)(WH + fo);
                s8v bl = *(const s8v*)(WL + fo);
                a3[t] = __builtin_amdgcn_mfma_f32_16x16x32_bf16(ah, bh, a3[t], 0, 0, 0);
                a3[t] = __builtin_amdgcn_mfma_f32_16x16x32_bf16(ah, bl, a3[t], 0, 0, 0);
                a3[t] = __builtin_amdgcn_mfma_f32_16x16x32_bf16(al, bh, a3[t], 0, 0, 0);
            }
        }

        if (s3 == 3) {
#pragma unroll
            for (int t = 0; t < 4; ++t) {
                int col = (4 * hf + t) * 16 + cc;
                float bb = bp[col];
#pragma unroll
                for (int r = 0; r < 4; ++r) {
                    int gr = row0 + 16 * sl + q * 4 + r;
                    if (gr < NN)
                        out[(size_t)gr * 128 + col] = fmaxf(a3[t][r] + bb, 0.f);
                }
            }
        } else {
            __syncthreads();
#pragma unroll
            for (int t = 0; t < 4; ++t) {
                int col = (4 * hf + t) * 16 + cc;
                float bb = bp[col];
#pragma unroll
                for (int r = 0; r < 4; ++r) {
                    int rl = 16 * sl + q * 4 + r;
                    float val = a3[t][r] + bb;
                    val = (s3 == 1) ? fmaxf(val, 0.f) : val * rm[r];
                    u16 h, lo; split2(val, h, lo);
                    Ah[rl][col] = h;
                    Al[rl][col] = lo;
                }
            }
            __syncthreads();
        }
    }
}

extern "C" void kernel_launch(void* const* d_in, const int* in_sizes, int n_in,
                              void* d_out, int out_size, void* d_ws, size_t ws_size,
                              hipStream_t stream) {
    const float* x   = (const float*)d_in[0];
    const int*   ei  = (const int*)d_in[1];
    const float* W1  = (const float*)d_in[2];
    const float* b1  = (const float*)d_in[3];
    const float* g1  = (const float*)d_in[4];
    const float* be1 = (const float*)d_in[5];
    const float* W2  = (const float*)d_in[6];
    const float* b2  = (const float*)d_in[7];
    const float* g2  = (const float*)d_in[8];
    const float* be2 = (const float*)d_in[9];
    // Wq/bq (10,11), Wk/bk (12,13) cancel: V gathered at dst => segment softmax sums to 1.
    const float* Wv  = (const float*)d_in[14];
    const float* bv  = (const float*)d_in[15];
    const float* Wo  = (const float*)d_in[16];
    const float* bo  = (const float*)d_in[17];

    float* out = (float*)d_out;
    char* ws = (char*)d_ws;

    // ---- gate: cooperative path only if true grid-wide co-residency is guaranteed ----
    static int coop_ok = -1;
    if (coop_ok < 0) {
        int dev = 0; hipGetDevice(&dev);
        int supported = 0;
        hipDeviceGetAttribute(&supported, hipDeviceAttributeCooperativeLaunch, dev);
        int ncu = 0;
        hipDeviceGetAttribute(&ncu, hipDeviceAttributeMultiprocessorCount, dev);
        int maxb = 0;
        hipError_t oe = hipOccupancyMaxActiveBlocksPerMultiprocessor(
            &maxb, (const void*)fused_k, 512, 0);
        coop_ok = (supported && oe == hipSuccess && ncu > 0 &&
                   (long)maxb * (long)ncu >= (long)NB) ? 1 : 0;
    }

    if (coop_ok == 1) {
        // coop ws layout (small; disjoint use, single path per run)
        float* mask = (float*)(ws);                    // 200 KB
        float* st   = (float*)(ws + 204800);           // 512 floats
        float* pst  = (float*)(ws + 208896);           // NB*256*4 = 800768 B
        u16*   fH   = (u16*)(ws + 1011712);            // 229 KB frag hi
        u16*   fL   = fH + TOTF;                       // 229 KB frag lo
        void* args[] = {
            (void*)&x, (void*)&ei, (void*)&W1, (void*)&b1, (void*)&g1, (void*)&be1,
            (void*)&W2, (void*)&b2, (void*)&g2, (void*)&be2,
            (void*)&Wv, (void*)&bv, (void*)&Wo, (void*)&bo,
            (void*)&mask, (void*)&st, (void*)&pst, (void*)&fH, (void*)&fL, (void*)&out
        };
        hipError_t le = hipLaunchCooperativeKernel((const void*)fused_k,
                                                   dim3(NB), dim3(512), args, 0, stream);
        if (le == hipSuccess) return;
        // fall through to the known-good pipeline on any launch failure
    }

    // ---- fallback: verbatim round-0 pipeline (known good, 227 us) ----
    float* buf  = (float*)(ws);                    // 25.6 MB raw x@W1+b1
    float* mask = (float*)(ws + 25600000);         // 200 KB
    float* st1  = (float*)(ws + 25800704);         // 1 KB
    float* st2  = st1 + 256;                       // 1 KB
    u16*   fH   = (u16*)(ws + 25804800);           // 229 KB frag hi
    u16*   fL   = fH + TOTF;                       // 229 KB frag lo
    float* pst  = (float*)(ws + 26263552);         // 800 KB partials

    hipMemsetAsync(mask, 0, NN * sizeof(float), stream);
    mask_scatter_k<<<dim3((NE + 255) / 256), dim3(256), 0, stream>>>(ei + NE, mask);
    prep_w_k<<<dim3((TOTF + 255) / 256), dim3(256), 0, stream>>>(W1, W2, Wv, Wo, fH, fL);

    dim3 gg(NB), bb(512);
    mgemm_k<8, 0, 1><<<gg, bb, 0, stream>>>(x, fH, fL, b1,
                                            nullptr, nullptr, nullptr, pst, buf);
    redstats_k<<<dim3(256), dim3(64), 0, stream>>>(pst, st1);
    mgemm_k<4, 1, 1><<<gg, bb, 0, stream>>>(buf, fH + 32768, fL + 32768, b2,
                                            st1, g1, be1, pst, out);
    redstats_k<<<dim3(256), dim3(64), 0, stream>>>(pst, st2);
    mmega_k<<<gg, bb, 0, stream>>>(out, fH + 49152, fL + 49152, bv, bo,
                                   st2, g2, be2, mask, out);
}

// Round 3
// 225.252 us; speedup vs baseline: 1.0165x; 1.0165x over previous
//
#include <hip/hip_runtime.h>
#include <hip/hip_cooperative_groups.h>

namespace cg = cooperative_groups;

#define NN 50000
#define NE 800000
#define NB 782        // ceil(NN/64)
#define TOTF 114688   // frag elems: W1 (8kc*4096=32768) + 5 matrices * 16384
#define GTHREADS (NB * 512)

typedef unsigned short u16;
typedef unsigned int u32;
typedef __attribute__((ext_vector_type(8))) short s8v;   // 8 bf16 = 4 VGPRs (MFMA A/B frag)
typedef __attribute__((ext_vector_type(4))) float f4v;   // MFMA C/D frag

// split fp32 into hi (truncated bf16) + lo (bf16 of remainder): f ~= hi + lo
__device__ __forceinline__ void split2(float f, u16& h, u16& lo) {
    u32 u = __float_as_uint(f);
    h = (u16)(u >> 16);
    float r = f - __uint_as_float(u & 0xFFFF0000u);   // exact
    lo = (u16)(__float_as_uint(r) >> 16);
}

__device__ __forceinline__ float join2(u16 h, u16 lo) {
    return __uint_as_float(((u32)h) << 16) + __uint_as_float(((u32)lo) << 16);
}

// ======================= fallback-path kernels (verbatim round-0) =======================

__global__ void mask_scatter_k(const int* __restrict__ dst, float* __restrict__ mask) {
    int i = blockIdx.x * blockDim.x + threadIdx.x;
    if (i < NE) mask[dst[i]] = 1.0f;
}

__global__ void prep_w_k(const float* __restrict__ W1, const float* __restrict__ W2,
                         const float* __restrict__ Wv, const float* __restrict__ Wo,
                         u16* __restrict__ fh, u16* __restrict__ fl) {
    int idx = blockIdx.x * 256 + threadIdx.x;
    if (idx >= TOTF) return;
    const float* W;
    int local;
    if (idx < 32768) { W = W1; local = idx; }
    else {
        int t = idx - 32768;
        int m = t >> 14;
        local = t & 16383;
        if (m == 0) W = W2;
        else if (m == 1) W = Wv;
        else if (m == 2) W = Wo;
        else if (m == 3) W = Wv + 16384;
        else W = Wo + 16384;
    }
    int j = local & 7, l = (local >> 3) & 63, nt = (local >> 9) & 7, kc = local >> 12;
    int k = kc * 32 + ((l >> 4) << 3) + j;
    int n = nt * 16 + (l & 15);
    u16 h, lo;
    split2(W[k * 128 + n], h, lo);
    fh[idx] = h;
    fl[idx] = lo;
}

__global__ __launch_bounds__(64)
void redstats_k(const float* __restrict__ pst, float* __restrict__ st) {
    int c = blockIdx.x;
    float s = 0.f;
    for (int b = threadIdx.x; b < NB; b += 64) s += pst[(size_t)b * 256 + c];
    s += __shfl_xor(s, 1);  s += __shfl_xor(s, 2);  s += __shfl_xor(s, 4);
    s += __shfl_xor(s, 8);  s += __shfl_xor(s, 16); s += __shfl_xor(s, 32);
    if (threadIdx.x == 0) st[c] = s;
}

template<int KC, int FOLD, int STATS>
__global__ __launch_bounds__(512, 6)
void mgemm_k(const float* __restrict__ A,
             const u16* __restrict__ fh, const u16* __restrict__ fl,
             const float* __restrict__ bias,
             const float* __restrict__ fst,
             const float* __restrict__ fg, const float* __restrict__ fbe,
             float* __restrict__ pst,
             float* __restrict__ C) {
    constexpr int KP = KC / 4;
    __shared__ __align__(16) u16 Ah[64][136];
    __shared__ __align__(16) u16 Al[64][136];
    __shared__ float scl[128], shf[128];
    const int tid = threadIdx.x;
    const int l = tid & 63, w = tid >> 6;
    const int q = l >> 4, cc = l & 15;
    const int sl = w >> 1, hf = w & 1;
    const int row0 = blockIdx.x * 64;

    if (FOLD && tid < 128) {
        float mean = fst[tid] * (1.0f / NN);
        float var = fst[128 + tid] * (1.0f / NN) - mean * mean;
        float rstd = rsqrtf(var + 1e-5f);
        float ga = fg[tid] * rstd;
        scl[tid] = ga;
        shf[tid] = fbe[tid] - mean * ga;
    }

    f4v zf = {0.f, 0.f, 0.f, 0.f};
    f4v acc[4];
#pragma unroll
    for (int t = 0; t < 4; ++t) acc[t] = zf;

    for (int p = 0; p < KP; ++p) {
        if (p > 0 || FOLD) __syncthreads();
#pragma unroll
        for (int it = 0; it < 4; ++it) {
            int lin = tid + 512 * it;
            int r = lin >> 5;
            int c4 = (lin & 31) * 4;
            int gr = row0 + r; if (gr > NN - 1) gr = NN - 1;
            float4 f = *(const float4*)(A + (size_t)gr * (KC * 32) + p * 128 + c4);
            float v[4] = {f.x, f.y, f.z, f.w};
            if (FOLD) {
#pragma unroll
                for (int m = 0; m < 4; ++m) {
                    float t = v[m] * scl[c4 + m] + shf[c4 + m];
                    v[m] = t > 0.f ? t : 0.f;
                }
            }
            ushort4 uh, ul;
            split2(v[0], uh.x, ul.x); split2(v[1], uh.y, ul.y);
            split2(v[2], uh.z, ul.z); split2(v[3], uh.w, ul.w);
            *(ushort4*)&Ah[r][c4] = uh;
            *(ushort4*)&Al[r][c4] = ul;
        }
        __syncthreads();
#pragma unroll
        for (int kc = 0; kc < 4; ++kc) {
            int kcg = p * 4 + kc;
            s8v ah = *(const s8v*)&Ah[16 * sl + cc][kc * 32 + q * 8];
            s8v al = *(const s8v*)&Al[16 * sl + cc][kc * 32 + q * 8];
#pragma unroll
            for (int t = 0; t < 4; ++t) {
                const int fo = kcg * 4096 + (4 * hf + t) * 512 + l * 8;
                s8v bh = *(const s8v*)(fh + fo);
                s8v bl = *(const s8v*)(fl + fo);
                acc[t] = __builtin_amdgcn_mfma_f32_16x16x32_bf16(ah, bh, acc[t], 0, 0, 0);
                acc[t] = __builtin_amdgcn_mfma_f32_16x16x32_bf16(ah, bl, acc[t], 0, 0, 0);
                acc[t] = __builtin_amdgcn_mfma_f32_16x16x32_bf16(al, bh, acc[t], 0, 0, 0);
            }
        }
    }

    float ps[4], pq[4];
#pragma unroll
    for (int t = 0; t < 4; ++t) { ps[t] = 0.f; pq[t] = 0.f; }
#pragma unroll
    for (int t = 0; t < 4; ++t) {
        int col = (4 * hf + t) * 16 + cc;
        float bb = bias[col];
#pragma unroll
        for (int r = 0; r < 4; ++r) {
            int gr = row0 + 16 * sl + q * 4 + r;
            float val = acc[t][r] + bb;
            if (gr < NN) {
                C[(size_t)gr * 128 + col] = val;
                if (STATS) { ps[t] += val; pq[t] += val * val; }
            }
        }
    }
    if (STATS) {
        __syncthreads();
        float* wredS = (float*)&Ah[0][0];
        float* wredQ = wredS + 512;
#pragma unroll
        for (int t = 0; t < 4; ++t) {
            ps[t] += __shfl_xor(ps[t], 16); ps[t] += __shfl_xor(ps[t], 32);
            pq[t] += __shfl_xor(pq[t], 16); pq[t] += __shfl_xor(pq[t], 32);
        }
        if (l < 16) {
#pragma unroll
            for (int t = 0; t < 4; ++t) {
                int col = (4 * hf + t) * 16 + l;
                wredS[sl * 128 + col] = ps[t];
                wredQ[sl * 128 + col] = pq[t];
            }
        }
        __syncthreads();
        if (tid < 256) {
            int c = tid & 127;
            const float* src = (tid < 128) ? wredS : wredQ;
            pst[(size_t)blockIdx.x * 256 + tid] =
                src[c] + src[128 + c] + src[256 + c] + src[384 + c];
        }
    }
}

__global__ __launch_bounds__(512, 6)
void mmega_k(const float* __restrict__ X,
             const u16* __restrict__ fh, const u16* __restrict__ fl,
             const float* __restrict__ bv, const float* __restrict__ bo,
             const float* __restrict__ fst,
             const float* __restrict__ fg, const float* __restrict__ fbe,
             const float* __restrict__ mask, float* __restrict__ out) {
    __shared__ __align__(16) u16 Ah[64][136];
    __shared__ __align__(16) u16 Al[64][136];
    __shared__ float scl[128], shf[128];
    const int tid = threadIdx.x;
    const int l = tid & 63, w = tid >> 6;
    const int q = l >> 4, cc = l & 15;
    const int sl = w >> 1, hf = w & 1;
    const int row0 = blockIdx.x * 64;

    if (tid < 128) {
        float mean = fst[tid] * (1.0f / NN);
        float var = fst[128 + tid] * (1.0f / NN) - mean * mean;
        float rstd = rsqrtf(var + 1e-5f);
        float ga = fg[tid] * rstd;
        scl[tid] = ga;
        shf[tid] = fbe[tid] - mean * ga;
    }
    __syncthreads();

    float rm[4];
#pragma unroll
    for (int r = 0; r < 4; ++r) {
        int gr = row0 + 16 * sl + q * 4 + r;
        rm[r] = (gr < NN) ? mask[gr] : 0.f;
    }

#pragma unroll
    for (int it = 0; it < 4; ++it) {
        int lin = tid + 512 * it;
        int r = lin >> 5;
        int c4 = (lin & 31) * 4;
        int gr = row0 + r; if (gr > NN - 1) gr = NN - 1;
        float4 f = *(const float4*)(X + (size_t)gr * 128 + c4);
        float v[4] = {f.x, f.y, f.z, f.w};
        ushort4 uh, ul;
#pragma unroll
        for (int m = 0; m < 4; ++m) {
            float t = v[m] * scl[c4 + m] + shf[c4 + m];
            v[m] = t > 0.f ? t : 0.f;
        }
        split2(v[0], uh.x, ul.x); split2(v[1], uh.y, ul.y);
        split2(v[2], uh.z, ul.z); split2(v[3], uh.w, ul.w);
        *(ushort4*)&Ah[r][c4] = uh;
        *(ushort4*)&Al[r][c4] = ul;
    }
    __syncthreads();

    f4v zf = {0.f, 0.f, 0.f, 0.f};
    for (int s = 0; s < 4; ++s) {
        const u16* WH = fh + s * 16384;
        const u16* WL = fl + s * 16384;
        const float* bp = (s == 0) ? bv : (s == 1) ? bo : (s == 2) ? (bv + 128) : (bo + 128);

        f4v acc[4];
#pragma unroll
        for (int t = 0; t < 4; ++t) acc[t] = zf;
#pragma unroll
        for (int kc = 0; kc < 4; ++kc) {
            s8v ah = *(const s8v*)&Ah[16 * sl + cc][kc * 32 + q * 8];
            s8v al = *(const s8v*)&Al[16 * sl + cc][kc * 32 + q * 8];
#pragma unroll
            for (int t = 0; t < 4; ++t) {
                const int fo = kc * 4096 + (4 * hf + t) * 512 + l * 8;
                s8v bh = *(const s8v*)(WH + fo);
                s8v bl = *(const s8v*)(WL + fo);
                acc[t] = __builtin_amdgcn_mfma_f32_16x16x32_bf16(ah, bh, acc[t], 0, 0, 0);
                acc[t] = __builtin_amdgcn_mfma_f32_16x16x32_bf16(ah, bl, acc[t], 0, 0, 0);
                acc[t] = __builtin_amdgcn_mfma_f32_16x16x32_bf16(al, bh, acc[t], 0, 0, 0);
            }
        }

        if (s == 3) {
#pragma unroll
            for (int t = 0; t < 4; ++t) {
                int col = (4 * hf + t) * 16 + cc;
                float bb = bp[col];
#pragma unroll
                for (int r = 0; r < 4; ++r) {
                    int gr = row0 + 16 * sl + q * 4 + r;
                    if (gr < NN)
                        out[(size_t)gr * 128 + col] = fmaxf(acc[t][r] + bb, 0.f);
                }
            }
        } else {
            __syncthreads();
#pragma unroll
            for (int t = 0; t < 4; ++t) {
                int col = (4 * hf + t) * 16 + cc;
                float bb = bp[col];
#pragma unroll
                for (int r = 0; r < 4; ++r) {
                    int rl = 16 * sl + q * 4 + r;
                    float val = acc[t][r] + bb;
                    val = (s == 1) ? fmaxf(val, 0.f) : val * rm[r];
                    u16 h, lo; split2(val, h, lo);
                    Ah[rl][col] = h;
                    Al[rl][col] = lo;
                }
            }
            __syncthreads();
        }
    }
}

// ======================= fused cooperative kernel =======================
// Layer intermediates live in LDS (split hi/lo planes) across grid.sync — nothing
// register-live across a sync, so __launch_bounds__(512,8)'s 64-reg cap causes no spills.
__global__ __launch_bounds__(512, 8)
void fused_k(const float* __restrict__ x, const int* __restrict__ ei,
             const float* __restrict__ W1, const float* __restrict__ b1,
             const float* __restrict__ g1, const float* __restrict__ be1,
             const float* __restrict__ W2, const float* __restrict__ b2,
             const float* __restrict__ g2, const float* __restrict__ be2,
             const float* __restrict__ Wv, const float* __restrict__ bv,
             const float* __restrict__ Wo, const float* __restrict__ bo,
             float* __restrict__ mask, float* __restrict__ st,
             float* __restrict__ pst,
             u16* __restrict__ fh, u16* __restrict__ fl,
             float* __restrict__ out) {
    __shared__ __align__(16) u16 Ah[64][136];
    __shared__ __align__(16) u16 Al[64][136];
    __shared__ float wredS[512], wredQ[512];     // separate: Ah/Al hold live data now
    const int tid = threadIdx.x;
    const int bid = blockIdx.x;
    const int l = tid & 63, w = tid >> 6;
    const int q = l >> 4, cc = l & 15;
    const int sl = w >> 1, hf = w & 1;
    const int row0 = bid * 64;
    const int gidx = bid * 512 + tid;

    cg::grid_group grid = cg::this_grid();

    // ---- phase 0: weight frag prep + mask zero ----
    if (gidx < TOTF) {
        const float* W;
        int local;
        if (gidx < 32768) { W = W1; local = gidx; }
        else {
            int tt = gidx - 32768;
            int m = tt >> 14;
            local = tt & 16383;
            if (m == 0) W = W2;
            else if (m == 1) W = Wv;
            else if (m == 2) W = Wo;
            else if (m == 3) W = Wv + 16384;
            else W = Wo + 16384;
        }
        int j = local & 7, el = (local >> 3) & 63, nt = (local >> 9) & 7, kc = local >> 12;
        int k = kc * 32 + ((el >> 4) << 3) + j;
        int n = nt * 16 + (el & 15);
        u16 h, lo;
        split2(W[k * 128 + n], h, lo);
        fh[gidx] = h;
        fl[gidx] = lo;
    }
    if (gidx < NN) mask[gidx] = 0.f;

    grid.sync();

    // ---- phase E1: enc1 GEMM x@W1 (K=256, 2 passes) ----
    f4v zf = {0.f, 0.f, 0.f, 0.f};
    {
        f4v acc[4];
#pragma unroll
        for (int t = 0; t < 4; ++t) acc[t] = zf;

        for (int p = 0; p < 2; ++p) {
            if (p) __syncthreads();
#pragma unroll
            for (int it = 0; it < 4; ++it) {
                int lin = tid + 512 * it;
                int r = lin >> 5;
                int c4 = (lin & 31) * 4;
                int gr = row0 + r; if (gr > NN - 1) gr = NN - 1;
                float4 f = *(const float4*)(x + (size_t)gr * 256 + p * 128 + c4);
                ushort4 uh, ul;
                split2(f.x, uh.x, ul.x); split2(f.y, uh.y, ul.y);
                split2(f.z, uh.z, ul.z); split2(f.w, uh.w, ul.w);
                *(ushort4*)&Ah[r][c4] = uh;
                *(ushort4*)&Al[r][c4] = ul;
            }
            __syncthreads();
#pragma unroll
            for (int kc = 0; kc < 4; ++kc) {
                int kcg = p * 4 + kc;
                s8v ah = *(const s8v*)&Ah[16 * sl + cc][kc * 32 + q * 8];
                s8v al = *(const s8v*)&Al[16 * sl + cc][kc * 32 + q * 8];
#pragma unroll
                for (int t = 0; t < 4; ++t) {
                    const int fo = kcg * 4096 + (4 * hf + t) * 512 + l * 8;
                    s8v bh = *(const s8v*)(fh + fo);
                    s8v bl = *(const s8v*)(fl + fo);
                    acc[t] = __builtin_amdgcn_mfma_f32_16x16x32_bf16(ah, bh, acc[t], 0, 0, 0);
                    acc[t] = __builtin_amdgcn_mfma_f32_16x16x32_bf16(ah, bl, acc[t], 0, 0, 0);
                    acc[t] = __builtin_amdgcn_mfma_f32_16x16x32_bf16(al, bh, acc[t], 0, 0, 0);
                }
            }
        }
        // epilogue: bias, stats partials (exact fp32), park val in LDS split planes
        float ps[4], pq[4];
#pragma unroll
        for (int t = 0; t < 4; ++t) {
            int col = (4 * hf + t) * 16 + cc;
            float bb = b1[col];
            ps[t] = 0.f; pq[t] = 0.f;
#pragma unroll
            for (int r = 0; r < 4; ++r) {
                float val = acc[t][r] + bb;
                acc[t][r] = val;
                int gr = row0 + 16 * sl + q * 4 + r;
                if (gr < NN) { ps[t] += val; pq[t] += val * val; }
            }
        }
        __syncthreads();                       // all MFMA ds_reads done before overwrite
#pragma unroll
        for (int t = 0; t < 4; ++t) {
            int col = (4 * hf + t) * 16 + cc;
#pragma unroll
            for (int r = 0; r < 4; ++r) {
                int rl = 16 * sl + q * 4 + r;
                u16 h, lo; split2(acc[t][r], h, lo);
                Ah[rl][col] = h;
                Al[rl][col] = lo;
            }
            ps[t] += __shfl_xor(ps[t], 16); ps[t] += __shfl_xor(ps[t], 32);
            pq[t] += __shfl_xor(pq[t], 16); pq[t] += __shfl_xor(pq[t], 32);
        }
        if (l < 16) {
#pragma unroll
            for (int t = 0; t < 4; ++t) {
                int col = (4 * hf + t) * 16 + l;
                wredS[sl * 128 + col] = ps[t];
                wredQ[sl * 128 + col] = pq[t];
            }
        }
        __syncthreads();
        if (tid < 256) {
            int c = tid & 127;
            const float* srcp = (tid < 128) ? wredS : wredQ;
            pst[(size_t)bid * 256 + tid] =
                srcp[c] + srcp[128 + c] + srcp[256 + c] + srcp[384 + c];
        }
    }

    grid.sync();

    // ---- red1 (exact redstats_k replica) + edge scatter ----
    if (bid < 256 && tid < 64) {
        float s = 0.f;
        for (int b = tid; b < NB; b += 64) s += pst[(size_t)b * 256 + bid];
        s += __shfl_xor(s, 1);  s += __shfl_xor(s, 2);  s += __shfl_xor(s, 4);
        s += __shfl_xor(s, 8);  s += __shfl_xor(s, 16); s += __shfl_xor(s, 32);
        if (tid == 0) st[bid] = s;
    }
    {
        const int* dstv = ei + NE;
        for (int eg = gidx; eg < NE; eg += GTHREADS) mask[dstv[eg]] = 1.0f;
    }

    grid.sync();

    // ---- phase E2: fold bn1+relu in-place in LDS, enc2 GEMM ----
#pragma unroll
    for (int t = 0; t < 4; ++t) {
        int col = (4 * hf + t) * 16 + cc;
        float mean = st[col] * (1.0f / NN);
        float var = st[128 + col] * (1.0f / NN) - mean * mean;
        float ga = g1[col] * rsqrtf(var + 1e-5f);
        float sh = be1[col] - mean * ga;
#pragma unroll
        for (int r = 0; r < 4; ++r) {
            int rl = 16 * sl + q * 4 + r;
            float v = join2(Ah[rl][col], Al[rl][col]) * ga + sh;
            v = v > 0.f ? v : 0.f;
            u16 h, lo; split2(v, h, lo);
            Ah[rl][col] = h;
            Al[rl][col] = lo;
        }
    }
    __syncthreads();

    {
        f4v acc2[4];
#pragma unroll
        for (int t = 0; t < 4; ++t) acc2[t] = zf;
#pragma unroll
        for (int kc = 0; kc < 4; ++kc) {
            s8v ah = *(const s8v*)&Ah[16 * sl + cc][kc * 32 + q * 8];
            s8v al = *(const s8v*)&Al[16 * sl + cc][kc * 32 + q * 8];
#pragma unroll
            for (int t = 0; t < 4; ++t) {
                const int fo = 32768 + kc * 4096 + (4 * hf + t) * 512 + l * 8;
                s8v bh = *(const s8v*)(fh + fo);
                s8v bl = *(const s8v*)(fl + fo);
                acc2[t] = __builtin_amdgcn_mfma_f32_16x16x32_bf16(ah, bh, acc2[t], 0, 0, 0);
                acc2[t] = __builtin_amdgcn_mfma_f32_16x16x32_bf16(ah, bl, acc2[t], 0, 0, 0);
                acc2[t] = __builtin_amdgcn_mfma_f32_16x16x32_bf16(al, bh, acc2[t], 0, 0, 0);
            }
        }
        float ps[4], pq[4];
#pragma unroll
        for (int t = 0; t < 4; ++t) {
            int col = (4 * hf + t) * 16 + cc;
            float bb = b2[col];
            ps[t] = 0.f; pq[t] = 0.f;
#pragma unroll
            for (int r = 0; r < 4; ++r) {
                float val = acc2[t][r] + bb;
                acc2[t][r] = val;
                int gr = row0 + 16 * sl + q * 4 + r;
                if (gr < NN) { ps[t] += val; pq[t] += val * val; }
            }
        }
        __syncthreads();                       // MFMA reads done before overwrite
#pragma unroll
        for (int t = 0; t < 4; ++t) {
            int col = (4 * hf + t) * 16 + cc;
#pragma unroll
            for (int r = 0; r < 4; ++r) {
                int rl = 16 * sl + q * 4 + r;
                u16 h, lo; split2(acc2[t][r], h, lo);
                Ah[rl][col] = h;
                Al[rl][col] = lo;
            }
            ps[t] += __shfl_xor(ps[t], 16); ps[t] += __shfl_xor(ps[t], 32);
            pq[t] += __shfl_xor(pq[t], 16); pq[t] += __shfl_xor(pq[t], 32);
        }
        if (l < 16) {
#pragma unroll
            for (int t = 0; t < 4; ++t) {
                int col = (4 * hf + t) * 16 + l;
                wredS[sl * 128 + col] = ps[t];
                wredQ[sl * 128 + col] = pq[t];
            }
        }
        __syncthreads();
        if (tid < 256) {
            int c = tid & 127;
            const float* srcp = (tid < 128) ? wredS : wredQ;
            pst[(size_t)bid * 256 + tid] =
                srcp[c] + srcp[128 + c] + srcp[256 + c] + srcp[384 + c];
        }
    }

    grid.sync();

    // ---- red2 ----
    if (bid < 256 && tid < 64) {
        float s = 0.f;
        for (int b = tid; b < NB; b += 64) s += pst[(size_t)b * 256 + bid];
        s += __shfl_xor(s, 1);  s += __shfl_xor(s, 2);  s += __shfl_xor(s, 4);
        s += __shfl_xor(s, 8);  s += __shfl_xor(s, 16); s += __shfl_xor(s, 32);
        if (tid == 0) st[256 + bid] = s;
    }

    grid.sync();

    // ---- phase M: fold bn2+relu in-place, 4-stage attn chain ----
    float rm[4];
#pragma unroll
    for (int r = 0; r < 4; ++r) {
        int gr = row0 + 16 * sl + q * 4 + r;
        rm[r] = (gr < NN) ? mask[gr] : 0.f;
    }
#pragma unroll
    for (int t = 0; t < 4; ++t) {
        int col = (4 * hf + t) * 16 + cc;
        float mean = st[256 + col] * (1.0f / NN);
        float var = st[384 + col] * (1.0f / NN) - mean * mean;
        float ga = g2[col] * rsqrtf(var + 1e-5f);
        float sh = be2[col] - mean * ga;
#pragma unroll
        for (int r = 0; r < 4; ++r) {
            int rl = 16 * sl + q * 4 + r;
            float v = join2(Ah[rl][col], Al[rl][col]) * ga + sh;
            v = v > 0.f ? v : 0.f;
            u16 h, lo; split2(v, h, lo);
            Ah[rl][col] = h;
            Al[rl][col] = lo;
        }
    }
    __syncthreads();

    for (int s3 = 0; s3 < 4; ++s3) {
        const u16* WH = fh + 49152 + s3 * 16384;
        const u16* WL = fl + 49152 + s3 * 16384;
        const float* bp = (s3 == 0) ? bv : (s3 == 1) ? bo : (s3 == 2) ? (bv + 128) : (bo + 128);

        f4v a3[4];
#pragma unroll
        for (int t = 0; t < 4; ++t) a3[t] = zf;
#pragma unroll
        for (int kc = 0; kc < 4; ++kc) {
            s8v ah = *(const s8v*)&Ah[16 * sl + cc][kc * 32 + q * 8];
            s8v al = *(const s8v*)&Al[16 * sl + cc][kc * 32 + q * 8];
#pragma unroll
            for (int t = 0; t < 4; ++t) {
                const int fo = kc * 4096 + (4 * hf + t) * 512 + l * 8;
                s8v bh = *(const s8v*)(WH + fo);
                s8v bl = *(const s8v*)(WL + fo);
                a3[t] = __builtin_amdgcn_mfma_f32_16x16x32_bf16(ah, bh, a3[t], 0, 0, 0);
                a3[t] = __builtin_amdgcn_mfma_f32_16x16x32_bf16(ah, bl, a3[t], 0, 0, 0);
                a3[t] = __builtin_amdgcn_mfma_f32_16x16x32_bf16(al, bh, a3[t], 0, 0, 0);
            }
        }

        if (s3 == 3) {
#pragma unroll
            for (int t = 0; t < 4; ++t) {
                int col = (4 * hf + t) * 16 + cc;
                float bb = bp[col];
#pragma unroll
                for (int r = 0; r < 4; ++r) {
                    int gr = row0 + 16 * sl + q * 4 + r;
                    if (gr < NN)
                        out[(size_t)gr * 128 + col] = fmaxf(a3[t][r] + bb, 0.f);
                }
            }
        } else {
            __syncthreads();
#pragma unroll
            for (int t = 0; t < 4; ++t) {
                int col = (4 * hf + t) * 16 + cc;
                float bb = bp[col];
#pragma unroll
                for (int r = 0; r < 4; ++r) {
                    int rl = 16 * sl + q * 4 + r;
                    float val = a3[t][r] + bb;
                    val = (s3 == 1) ? fmaxf(val, 0.f) : val * rm[r];
                    u16 h, lo; split2(val, h, lo);
                    Ah[rl][col] = h;
                    Al[rl][col] = lo;
                }
            }
            __syncthreads();
        }
    }
}

extern "C" void kernel_launch(void* const* d_in, const int* in_sizes, int n_in,
                              void* d_out, int out_size, void* d_ws, size_t ws_size,
                              hipStream_t stream) {
    const float* x   = (const float*)d_in[0];
    const int*   ei  = (const int*)d_in[1];
    const float* W1  = (const float*)d_in[2];
    const float* b1  = (const float*)d_in[3];
    const float* g1  = (const float*)d_in[4];
    const float* be1 = (const float*)d_in[5];
    const float* W2  = (const float*)d_in[6];
    const float* b2  = (const float*)d_in[7];
    const float* g2  = (const float*)d_in[8];
    const float* be2 = (const float*)d_in[9];
    // Wq/bq (10,11), Wk/bk (12,13) cancel: V gathered at dst => segment softmax sums to 1.
    const float* Wv  = (const float*)d_in[14];
    const float* bv  = (const float*)d_in[15];
    const float* Wo  = (const float*)d_in[16];
    const float* bo  = (const float*)d_in[17];

    float* out = (float*)d_out;
    char* ws = (char*)d_ws;

    // ---- gate: cooperative path only if true grid-wide co-residency is guaranteed ----
    static int coop_ok = -1;
    if (coop_ok < 0) {
        int dev = 0; hipGetDevice(&dev);
        int supported = 0;
        hipDeviceGetAttribute(&supported, hipDeviceAttributeCooperativeLaunch, dev);
        int ncu = 0;
        hipDeviceGetAttribute(&ncu, hipDeviceAttributeMultiprocessorCount, dev);
        int maxb = 0;
        hipError_t oe = hipOccupancyMaxActiveBlocksPerMultiprocessor(
            &maxb, (const void*)fused_k, 512, 0);
        coop_ok = (supported && oe == hipSuccess && ncu > 0 &&
                   (long)maxb * (long)ncu >= (long)NB) ? 1 : 0;
    }

    if (coop_ok == 1) {
        float* mask = (float*)(ws);                    // 200 KB
        float* st   = (float*)(ws + 204800);           // 512 floats
        float* pst  = (float*)(ws + 208896);           // NB*256*4 = 800768 B
        u16*   fH   = (u16*)(ws + 1011712);            // 229 KB frag hi
        u16*   fL   = fH + TOTF;                       // 229 KB frag lo
        void* args[] = {
            (void*)&x, (void*)&ei, (void*)&W1, (void*)&b1, (void*)&g1, (void*)&be1,
            (void*)&W2, (void*)&b2, (void*)&g2, (void*)&be2,
            (void*)&Wv, (void*)&bv, (void*)&Wo, (void*)&bo,
            (void*)&mask, (void*)&st, (void*)&pst, (void*)&fH, (void*)&fL, (void*)&out
        };
        hipError_t le = hipLaunchCooperativeKernel((const void*)fused_k,
                                                   dim3(NB), dim3(512), args, 0, stream);
        if (le == hipSuccess) return;
        // fall through to the known-good pipeline on any launch failure
    }

    // ---- fallback: verbatim round-0 pipeline (known good, 227 us) ----
    float* buf  = (float*)(ws);                    // 25.6 MB raw x@W1+b1
    float* mask = (float*)(ws + 25600000);         // 200 KB
    float* st1  = (float*)(ws + 25800704);         // 1 KB
    float* st2  = st1 + 256;                       // 1 KB
    u16*   fH   = (u16*)(ws + 25804800);           // 229 KB frag hi
    u16*   fL   = fH + TOTF;                       // 229 KB frag lo
    float* pst  = (float*)(ws + 26263552);         // 800 KB partials

    hipMemsetAsync(mask, 0, NN * sizeof(float), stream);
    mask_scatter_k<<<dim3((NE + 255) / 256), dim3(256), 0, stream>>>(ei + NE, mask);
    prep_w_k<<<dim3((TOTF + 255) / 256), dim3(256), 0, stream>>>(W1, W2, Wv, Wo, fH, fL);

    dim3 gg(NB), bb(512);
    mgemm_k<8, 0, 1><<<gg, bb, 0, stream>>>(x, fH, fL, b1,
                                            nullptr, nullptr, nullptr, pst, buf);
    redstats_k<<<dim3(256), dim3(64), 0, stream>>>(pst, st1);
    mgemm_k<4, 1, 1><<<gg, bb, 0, stream>>>(buf, fH + 32768, fL + 32768, b2,
                                            st1, g1, be1, pst, out);
    redstats_k<<<dim3(256), dim3(64), 0, stream>>>(pst, st2);
    mmega_k<<<gg, bb, 0, stream>>>(out, fH + 49152, fL + 49152, bv, bo,
                                   st2, g2, be2, mask, out);
}